// Round 1
// baseline (362.611 us; speedup 1.0000x reference)
//
#include <hip/hip_runtime.h>
#include <hip/hip_bf16.h>

#define D 128           // D_IN == D_OUT == 128
#define GM_ROWS 64      // rows per GEMM block
#define SP_ROWS 4       // rows per SpMM block (1 wave each)

// ---------------------------------------------------------------------------
// Kernel 1: w_input = x @ W^T   (fp32 vector ALU; no fp32 MFMA on CDNA4)
//   x: [N,128], W: [128,128] row-major (W[d][k]), out wi: [N,128]
// ---------------------------------------------------------------------------
__global__ __launch_bounds__(256) void gemm_xwt(const float* __restrict__ x,
                                                const float* __restrict__ W,
                                                float* __restrict__ wi,
                                                int nrows) {
    // Wl[k][d] = W[d][k], padded stride 132 floats (16B-aligned rows, no pow2 bank stride)
    __shared__ __align__(16) float Wl[D * 132];
    __shared__ __align__(16) float Xl[GM_ROWS * 132];

    const int tid = threadIdx.x;
    const int row0 = blockIdx.x * GM_ROWS;

    // stage W (transposed) into LDS: global reads coalesced over k
    for (int i = tid; i < D * D; i += 256) {
        int d = i >> 7, k = i & 127;
        Wl[k * 132 + d] = W[i];          // W[d][k]
    }
    // stage x tile
    for (int i = tid; i < GM_ROWS * D; i += 256) {
        int m = i >> 7, k = i & 127;
        int gr = row0 + m;
        Xl[m * 132 + k] = (gr < nrows) ? x[(size_t)gr * D + k] : 0.0f;
    }
    __syncthreads();

    // thread tile: 8 rows x 4 cols
    const int d0 = (tid & 31) * 4;       // col group
    const int m0 = (tid >> 5) * 8;       // row group
    float acc[8][4] = {};

    for (int k = 0; k < D; k += 4) {
        float4 wv[4];
#pragma unroll
        for (int kk = 0; kk < 4; ++kk)
            wv[kk] = *(const float4*)&Wl[(k + kk) * 132 + d0];
#pragma unroll
        for (int i = 0; i < 8; ++i) {
            float4 xv = *(const float4*)&Xl[(m0 + i) * 132 + k];
            float xk[4] = {xv.x, xv.y, xv.z, xv.w};
#pragma unroll
            for (int kk = 0; kk < 4; ++kk) {
                const float* wvf = (const float*)&wv[kk];
#pragma unroll
                for (int j = 0; j < 4; ++j)
                    acc[i][j] = fmaf(xk[kk], wvf[j], acc[i][j]);
            }
        }
    }

#pragma unroll
    for (int i = 0; i < 8; ++i) {
        int gr = row0 + m0 + i;
        if (gr < nrows) {
            float4 o = make_float4(acc[i][0], acc[i][1], acc[i][2], acc[i][3]);
            *(float4*)&wi[(size_t)gr * D + d0] = o;
        }
    }
}

// ---------------------------------------------------------------------------
// Kernel 2: out[r] = relu(bias + sum_{e: rows[e]==r} vals[e]*wi[cols[e]])
//   adj_rows sorted -> per-row edge range via binary search (wave-uniform).
//   One wave per row; lane owns 2 channels (float2).
// ---------------------------------------------------------------------------
__device__ __forceinline__ int lower_bound(const int* __restrict__ a, int n, int key) {
    int lo = 0, hi = n;
    while (lo < hi) {
        int mid = (lo + hi) >> 1;
        if (a[mid] < key) lo = mid + 1; else hi = mid;
    }
    return lo;
}

__global__ __launch_bounds__(256) void spmm_relu(const float* __restrict__ wi,
                                                 const int* __restrict__ rows,
                                                 const int* __restrict__ cols,
                                                 const float* __restrict__ vals,
                                                 const float* __restrict__ bias,
                                                 float* __restrict__ out,
                                                 int n, int e) {
    const int wave = threadIdx.x >> 6;
    const int lane = threadIdx.x & 63;
    const int r = blockIdx.x * SP_ROWS + wave;
    if (r >= n) return;

    const int start = lower_bound(rows, e, r);
    const int end   = lower_bound(rows, e, r + 1);

    float ax = 0.0f, ay = 0.0f;

    for (int base = start; base < end; base += 64) {
        const int cnt = min(64, end - base);
        int   c = 0;
        float v = 0.0f;
        if (lane < cnt) {
            c = cols[base + lane];
            v = vals[base + lane];
        }
        int i = 0;
        // 4-deep unroll for gather ILP
        for (; i + 4 <= cnt; i += 4) {
            int   c0 = __shfl(c, i),     c1 = __shfl(c, i + 1);
            int   c2 = __shfl(c, i + 2), c3 = __shfl(c, i + 3);
            float v0 = __shfl(v, i),     v1 = __shfl(v, i + 1);
            float v2 = __shfl(v, i + 2), v3 = __shfl(v, i + 3);
            float2 w0 = *(const float2*)(wi + (size_t)c0 * D + lane * 2);
            float2 w1 = *(const float2*)(wi + (size_t)c1 * D + lane * 2);
            float2 w2 = *(const float2*)(wi + (size_t)c2 * D + lane * 2);
            float2 w3 = *(const float2*)(wi + (size_t)c3 * D + lane * 2);
            ax = fmaf(v0, w0.x, ax); ay = fmaf(v0, w0.y, ay);
            ax = fmaf(v1, w1.x, ax); ay = fmaf(v1, w1.y, ay);
            ax = fmaf(v2, w2.x, ax); ay = fmaf(v2, w2.y, ay);
            ax = fmaf(v3, w3.x, ax); ay = fmaf(v3, w3.y, ay);
        }
        for (; i < cnt; ++i) {
            int   ci = __shfl(c, i);
            float vi = __shfl(v, i);
            float2 w0 = *(const float2*)(wi + (size_t)ci * D + lane * 2);
            ax = fmaf(vi, w0.x, ax); ay = fmaf(vi, w0.y, ay);
        }
    }

    const float2 b2 = *(const float2*)(bias + lane * 2);
    float2 o;
    o.x = fmaxf(ax + b2.x, 0.0f);
    o.y = fmaxf(ay + b2.y, 0.0f);
    *(float2*)(out + (size_t)r * D + lane * 2) = o;
}

// ---------------------------------------------------------------------------
extern "C" void kernel_launch(void* const* d_in, const int* in_sizes, int n_in,
                              void* d_out, int out_size, void* d_ws, size_t ws_size,
                              hipStream_t stream) {
    const float* x        = (const float*)d_in[0];
    const int*   adj_rows = (const int*)d_in[1];
    const int*   adj_cols = (const int*)d_in[2];
    const float* adj_vals = (const float*)d_in[3];
    const float* weight   = (const float*)d_in[4];
    const float* bias     = (const float*)d_in[5];
    float*       out      = (float*)d_out;

    const int n = in_sizes[0] / D;   // 100000
    const int e = in_sizes[1];       // 1600000

    float* wi = (float*)d_ws;        // [n,128] fp32 = 51.2 MB

    const int gemm_blocks = (n + GM_ROWS - 1) / GM_ROWS;
    gemm_xwt<<<gemm_blocks, 256, 0, stream>>>(x, weight, wi, n);

    const int spmm_blocks = (n + SP_ROWS - 1) / SP_ROWS;
    spmm_relu<<<spmm_blocks, 256, 0, stream>>>(wi, adj_rows, adj_cols, adj_vals,
                                               bias, out, n, e);
}

// Round 2
// 106.275 us; speedup vs baseline: 3.4120x; 3.4120x over previous
//
#include <hip/hip_runtime.h>
#include <hip/hip_bf16.h>

#define D 128

typedef __attribute__((ext_vector_type(8))) short bf16x8;
typedef __attribute__((ext_vector_type(4))) float f32x4;

// float -> bf16 bits, round-to-nearest-even (inputs are finite randoms)
__device__ __forceinline__ unsigned short f2bf(float f) {
    union { float f; unsigned u; } uf{f};
    unsigned r = uf.u + 0x7fffu + ((uf.u >> 16) & 1u);
    return (unsigned short)(r >> 16);
}
__device__ __forceinline__ unsigned pack2(float a, float b) {
    return (unsigned)f2bf(a) | ((unsigned)f2bf(b) << 16);
}
__device__ __forceinline__ float bflo(unsigned u) {
    union { unsigned u; float f; } c{u << 16};
    return c.f;
}
__device__ __forceinline__ float bfhi(unsigned u) {
    union { unsigned u; float f; } c{u & 0xffff0000u};
    return c.f;
}

// ---------------------------------------------------------------------------
// Kernel 0: row_start/row_end from sorted adj_rows (row_start pre-memset -1)
// ---------------------------------------------------------------------------
__global__ __launch_bounds__(256) void build_rowptr(const int* __restrict__ rows,
                                                    int* __restrict__ row_start,
                                                    int* __restrict__ row_end,
                                                    int e) {
    int i = blockIdx.x * 256 + threadIdx.x;
    if (i >= e) return;
    int r = rows[i];
    if (i == 0 || rows[i - 1] != r) row_start[r] = i;
    if (i == e - 1 || rows[i + 1] != r) row_end[r] = i + 1;
}

// ---------------------------------------------------------------------------
// Kernel 1: wi = bf16(x @ W^T) via MFMA 16x16x32_bf16.
//   Tile: 128 rows x 128 cols per 256-thread block (4 waves x 32 rows).
//   Xs/Ws staged bf16 in LDS with xor-swizzle (idx ^= (row&7)<<3, ushort units)
// ---------------------------------------------------------------------------
__global__ __launch_bounds__(256) void gemm_mfma(const float* __restrict__ x,
                                                 const float* __restrict__ W,
                                                 unsigned short* __restrict__ wi,
                                                 int nrows) {
    __shared__ __align__(16) unsigned short Xs[128 * 128];
    __shared__ __align__(16) unsigned short Ws[128 * 128];

    const int tid = threadIdx.x;
    const int row0 = blockIdx.x * 128;

    // stage: 16384 floats each for W and x-tile; thread t covers f = it*1024 + t*4
#pragma unroll 4
    for (int it = 0; it < 16; ++it) {
        int f = it * 1024 + tid * 4;
        int r = f >> 7, k = f & 127;
        int idx = (r * 128 + k) ^ ((r & 7) << 3);

        float4 wv = *(const float4*)(W + f);
        *(uint2*)&Ws[idx] = make_uint2(pack2(wv.x, wv.y), pack2(wv.z, wv.w));

        int gr = row0 + r;
        float4 xv = (gr < nrows) ? *(const float4*)(x + (size_t)gr * D + k)
                                 : make_float4(0.f, 0.f, 0.f, 0.f);
        *(uint2*)&Xs[idx] = make_uint2(pack2(xv.x, xv.y), pack2(xv.z, xv.w));
    }
    __syncthreads();

    const int lane = tid & 63;
    const int wv_id = tid >> 6;       // wave 0..3 -> rows wv_id*32 .. +31
    const int m_base = wv_id * 32;
    const int lrow = lane & 15;
    const int lk8 = (lane >> 4) * 8;

    // A fragments: 2 row-blocks x 4 k-blocks, held in regs
    bf16x8 afrag[2][4];
#pragma unroll
    for (int rb = 0; rb < 2; ++rb)
#pragma unroll
        for (int kb = 0; kb < 4; ++kb) {
            int r = m_base + rb * 16 + lrow;
            int k = kb * 32 + lk8;
            int idx = (r * 128 + k) ^ ((r & 7) << 3);
            afrag[rb][kb] = *(const bf16x8*)&Xs[idx];
        }

    f32x4 acc[2][8];
#pragma unroll
    for (int rb = 0; rb < 2; ++rb)
#pragma unroll
        for (int nb = 0; nb < 8; ++nb)
            acc[rb][nb] = (f32x4){0.f, 0.f, 0.f, 0.f};

#pragma unroll
    for (int nb = 0; nb < 8; ++nb) {
#pragma unroll
        for (int kb = 0; kb < 4; ++kb) {
            int nr = nb * 16 + lrow;
            int k = kb * 32 + lk8;
            int idx = (nr * 128 + k) ^ ((nr & 7) << 3);
            bf16x8 bfrag = *(const bf16x8*)&Ws[idx];
            acc[0][nb] = __builtin_amdgcn_mfma_f32_16x16x32_bf16(afrag[0][kb], bfrag, acc[0][nb], 0, 0, 0);
            acc[1][nb] = __builtin_amdgcn_mfma_f32_16x16x32_bf16(afrag[1][kb], bfrag, acc[1][nb], 0, 0, 0);
        }
    }

    // C/D layout: col = lane&15 (output channel), row = (lane>>4)*4 + j
#pragma unroll
    for (int rb = 0; rb < 2; ++rb)
#pragma unroll
        for (int j = 0; j < 4; ++j) {
            int gr = row0 + m_base + rb * 16 + (lane >> 4) * 4 + j;
            if (gr < nrows) {
#pragma unroll
                for (int nb = 0; nb < 8; ++nb)
                    wi[(size_t)gr * D + nb * 16 + lrow] = f2bf(acc[rb][nb][j]);
            }
        }
}

// ---------------------------------------------------------------------------
// Kernel 2: out[r] = relu(bias + sum vals[e]*wi[cols[e]])  (wi is bf16)
//   1 wave per row; 4 edges per iteration: 16 lanes x uint4 = one 256B row.
// ---------------------------------------------------------------------------
__global__ __launch_bounds__(256) void spmm_relu(const unsigned short* __restrict__ wi,
                                                 const int* __restrict__ row_start,
                                                 const int* __restrict__ row_end,
                                                 const int* __restrict__ cols,
                                                 const float* __restrict__ vals,
                                                 const float* __restrict__ bias,
                                                 float* __restrict__ out,
                                                 int n) {
    const int wave = threadIdx.x >> 6;
    const int lane = threadIdx.x & 63;
    const int r = blockIdx.x * 4 + wave;
    if (r >= n) return;

    float acc[8] = {0.f, 0.f, 0.f, 0.f, 0.f, 0.f, 0.f, 0.f};

    const int start = row_start[r];
    if (start >= 0) {
        const int end = row_end[r];
        const int ch = (lane & 15) * 8;   // channel base this lane gathers
        const int sub = lane >> 4;        // which edge of the quad

        for (int base = start; base < end; base += 64) {
            const int cnt = min(64, end - base);
            int c = 0;
            float v = 0.f;
            if (lane < cnt) {
                c = cols[base + lane];
                v = vals[base + lane];
            }
            for (int p = 0; p * 4 < cnt; ++p) {
                int idx = p * 4 + sub;
                int cp = __shfl(c, idx);
                float vp = __shfl(v, idx);
                uint4 u = *(const uint4*)(wi + (size_t)cp * D + ch);
                acc[0] = fmaf(vp, bflo(u.x), acc[0]);
                acc[1] = fmaf(vp, bfhi(u.x), acc[1]);
                acc[2] = fmaf(vp, bflo(u.y), acc[2]);
                acc[3] = fmaf(vp, bfhi(u.y), acc[3]);
                acc[4] = fmaf(vp, bflo(u.z), acc[4]);
                acc[5] = fmaf(vp, bfhi(u.z), acc[5]);
                acc[6] = fmaf(vp, bflo(u.w), acc[6]);
                acc[7] = fmaf(vp, bfhi(u.w), acc[7]);
            }
        }
    }

    // combine the 4 edge-subgroups (lanes l, l^16, l^32, l^48 share channels)
#pragma unroll
    for (int j = 0; j < 8; ++j) {
        acc[j] += __shfl_xor(acc[j], 16);
        acc[j] += __shfl_xor(acc[j], 32);
    }

    if (lane < 16) {
        const int ch = lane * 8;
        float4 b0 = *(const float4*)(bias + ch);
        float4 b1 = *(const float4*)(bias + ch + 4);
        float4 o0, o1;
        o0.x = fmaxf(acc[0] + b0.x, 0.f);
        o0.y = fmaxf(acc[1] + b0.y, 0.f);
        o0.z = fmaxf(acc[2] + b0.z, 0.f);
        o0.w = fmaxf(acc[3] + b0.w, 0.f);
        o1.x = fmaxf(acc[4] + b1.x, 0.f);
        o1.y = fmaxf(acc[5] + b1.y, 0.f);
        o1.z = fmaxf(acc[6] + b1.z, 0.f);
        o1.w = fmaxf(acc[7] + b1.w, 0.f);
        *(float4*)(out + (size_t)r * D + ch) = o0;
        *(float4*)(out + (size_t)r * D + ch + 4) = o1;
    }
}

// ---------------------------------------------------------------------------
extern "C" void kernel_launch(void* const* d_in, const int* in_sizes, int n_in,
                              void* d_out, int out_size, void* d_ws, size_t ws_size,
                              hipStream_t stream) {
    const float* x        = (const float*)d_in[0];
    const int*   adj_rows = (const int*)d_in[1];
    const int*   adj_cols = (const int*)d_in[2];
    const float* adj_vals = (const float*)d_in[3];
    const float* weight   = (const float*)d_in[4];
    const float* bias     = (const float*)d_in[5];
    float*       out      = (float*)d_out;

    const int n = in_sizes[0] / D;   // 100000
    const int e = in_sizes[1];       // 1600000

    // workspace layout
    unsigned short* wi = (unsigned short*)d_ws;                 // n*128 bf16 = 25.6 MB
    size_t off = ((size_t)n * D * sizeof(unsigned short) + 255) & ~(size_t)255;
    int* row_start = (int*)((char*)d_ws + off);
    int* row_end   = row_start + n;

    hipMemsetAsync(row_start, 0xFF, (size_t)n * sizeof(int), stream);
    build_rowptr<<<(e + 255) / 256, 256, 0, stream>>>(adj_rows, row_start, row_end, e);

    gemm_mfma<<<(n + 127) / 128, 256, 0, stream>>>(x, weight, wi, n);

    spmm_relu<<<(n + 3) / 4, 256, 0, stream>>>(wi, row_start, row_end,
                                               adj_cols, adj_vals, bias, out, n);
}

// Round 3
// 104.660 us; speedup vs baseline: 3.4646x; 1.0154x over previous
//
#include <hip/hip_runtime.h>
#include <hip/hip_bf16.h>

#define D 128

typedef __attribute__((ext_vector_type(8))) short bf16x8;
typedef __attribute__((ext_vector_type(4))) float f32x4;

// float -> bf16 bits, round-to-nearest-even
__device__ __forceinline__ unsigned short f2bf(float f) {
    union { float f; unsigned u; } uf{f};
    unsigned r = uf.u + 0x7fffu + ((uf.u >> 16) & 1u);
    return (unsigned short)(r >> 16);
}
__device__ __forceinline__ unsigned pack2(float a, float b) {
    return (unsigned)f2bf(a) | ((unsigned)f2bf(b) << 16);
}
__device__ __forceinline__ float bflo(unsigned u) {
    union { unsigned u; float f; } c{u << 16};
    return c.f;
}
__device__ __forceinline__ float bfhi(unsigned u) {
    union { unsigned u; float f; } c{u & 0xffff0000u};
    return c.f;
}

#define FMA8(A, vv, u) \
    A[0] = fmaf(vv, bflo(u.x), A[0]); A[1] = fmaf(vv, bfhi(u.x), A[1]); \
    A[2] = fmaf(vv, bflo(u.y), A[2]); A[3] = fmaf(vv, bfhi(u.y), A[3]); \
    A[4] = fmaf(vv, bflo(u.z), A[4]); A[5] = fmaf(vv, bfhi(u.z), A[5]); \
    A[6] = fmaf(vv, bflo(u.w), A[6]); A[7] = fmaf(vv, bfhi(u.w), A[7]);

// ---------------------------------------------------------------------------
// Kernel 0: row_start/row_end from sorted adj_rows (row_start pre-memset -1),
//           plus one-time W fp32 -> bf16 conversion (16384 elements).
// ---------------------------------------------------------------------------
__global__ __launch_bounds__(256) void build_rowptr(const int* __restrict__ rows,
                                                    const float* __restrict__ W,
                                                    unsigned short* __restrict__ wbf,
                                                    int* __restrict__ row_start,
                                                    int* __restrict__ row_end,
                                                    int e) {
    int i = blockIdx.x * 256 + threadIdx.x;
    if (i < D * D) wbf[i] = f2bf(W[i]);
    if (i >= e) return;
    int r = rows[i];
    if (i == 0 || rows[i - 1] != r) row_start[r] = i;
    if (i == e - 1 || rows[i + 1] != r) row_end[r] = i + 1;
}

// ---------------------------------------------------------------------------
// Kernel 1: wi = bf16(x @ W^T) via MFMA 16x16x32_bf16.
//   128-row tile per 256-thread block; only Xs in LDS (32 KB, xor-swizzled);
//   B fragments read directly from bf16 W in global (L1-resident 32 KB).
// ---------------------------------------------------------------------------
__global__ __launch_bounds__(256, 3) void gemm_mfma(const float* __restrict__ x,
                                                    const unsigned short* __restrict__ wbf,
                                                    unsigned short* __restrict__ wi,
                                                    int nrows) {
    __shared__ __align__(16) unsigned short Xs[128 * 128];

    const int tid = threadIdx.x;
    const int row0 = blockIdx.x * 128;

#pragma unroll
    for (int it = 0; it < 16; ++it) {
        int f = it * 1024 + tid * 4;
        int r = f >> 7, k = f & 127;
        int idx = (r * 128 + k) ^ ((r & 7) << 3);
        int gr = row0 + r;
        float4 xv = (gr < nrows) ? *(const float4*)(x + (size_t)gr * D + k)
                                 : make_float4(0.f, 0.f, 0.f, 0.f);
        *(uint2*)&Xs[idx] = make_uint2(pack2(xv.x, xv.y), pack2(xv.z, xv.w));
    }
    __syncthreads();

    const int lane = tid & 63;
    const int m_base = (tid >> 6) * 32;   // wave's 32 rows
    const int lrow = lane & 15;
    const int lk8 = (lane >> 4) * 8;

    bf16x8 afrag[2][4];
#pragma unroll
    for (int rb = 0; rb < 2; ++rb)
#pragma unroll
        for (int kb = 0; kb < 4; ++kb) {
            int r = m_base + rb * 16 + lrow;
            int k = kb * 32 + lk8;
            int idx = (r * 128 + k) ^ ((r & 7) << 3);
            afrag[rb][kb] = *(const bf16x8*)&Xs[idx];
        }

    f32x4 acc[2][8];
#pragma unroll
    for (int rb = 0; rb < 2; ++rb)
#pragma unroll
        for (int nb = 0; nb < 8; ++nb)
            acc[rb][nb] = (f32x4){0.f, 0.f, 0.f, 0.f};

#pragma unroll
    for (int nb = 0; nb < 8; ++nb) {
#pragma unroll
        for (int kb = 0; kb < 4; ++kb) {
            bf16x8 bfrag = *(const bf16x8*)(wbf + (nb * 16 + lrow) * 128 + kb * 32 + lk8);
            acc[0][nb] = __builtin_amdgcn_mfma_f32_16x16x32_bf16(afrag[0][kb], bfrag, acc[0][nb], 0, 0, 0);
            acc[1][nb] = __builtin_amdgcn_mfma_f32_16x16x32_bf16(afrag[1][kb], bfrag, acc[1][nb], 0, 0, 0);
        }
    }

    // C/D layout: col = lane&15, row = (lane>>4)*4 + j
#pragma unroll
    for (int rb = 0; rb < 2; ++rb)
#pragma unroll
        for (int j = 0; j < 4; ++j) {
            int gr = row0 + m_base + rb * 16 + (lane >> 4) * 4 + j;
            if (gr < nrows) {
#pragma unroll
                for (int nb = 0; nb < 8; ++nb)
                    wi[(size_t)gr * D + nb * 16 + lrow] = f2bf(acc[rb][nb][j]);
            }
        }
}

// ---------------------------------------------------------------------------
// Kernel 2: out[r] = relu(bias + sum vals[e]*wi[cols[e]])  (wi is bf16)
//   1 wave/row; 16 edges per inner iteration -> 4 gathers/lane in flight.
// ---------------------------------------------------------------------------
__global__ __launch_bounds__(256) void spmm_relu(const unsigned short* __restrict__ wi,
                                                 const int* __restrict__ row_start,
                                                 const int* __restrict__ row_end,
                                                 const int* __restrict__ cols,
                                                 const float* __restrict__ vals,
                                                 const float* __restrict__ bias,
                                                 float* __restrict__ out,
                                                 int n) {
    const int lane = threadIdx.x & 63;
    const int r = blockIdx.x * 4 + (threadIdx.x >> 6);
    if (r >= n) return;

    float a0[8] = {0.f, 0.f, 0.f, 0.f, 0.f, 0.f, 0.f, 0.f};
    float a1[8] = {0.f, 0.f, 0.f, 0.f, 0.f, 0.f, 0.f, 0.f};

    const int start = row_start[r];
    if (start >= 0) {
        const int end = row_end[r];
        const int ch = (lane & 15) * 8;   // channel base this lane gathers
        const int sub = lane >> 4;        // which edge of each quad

        for (int base = start; base < end; base += 64) {
            const int cnt = min(64, end - base);
            int c = 0;
            float v = 0.f;
            if (lane < cnt) {
                c = cols[base + lane];
                v = vals[base + lane];
            }
            // 16 edges per iteration: 4 independent gathers/lane in flight
            for (int q = 0; q * 4 < cnt; q += 4) {
                const int i0 = q * 4 + sub;           // max 51, +12 <= 63
                int   c0 = __shfl(c, i0),     c1 = __shfl(c, i0 + 4);
                int   c2 = __shfl(c, i0 + 8), c3 = __shfl(c, i0 + 12);
                float v0 = __shfl(v, i0),     v1 = __shfl(v, i0 + 4);
                float v2 = __shfl(v, i0 + 8), v3 = __shfl(v, i0 + 12);
                uint4 u0 = *(const uint4*)(wi + (size_t)c0 * D + ch);
                uint4 u1 = *(const uint4*)(wi + (size_t)c1 * D + ch);
                uint4 u2 = *(const uint4*)(wi + (size_t)c2 * D + ch);
                uint4 u3 = *(const uint4*)(wi + (size_t)c3 * D + ch);
                FMA8(a0, v0, u0); FMA8(a1, v1, u1);
                FMA8(a0, v2, u2); FMA8(a1, v3, u3);
            }
        }
    }

    float acc[8];
#pragma unroll
    for (int j = 0; j < 8; ++j) {
        float s = a0[j] + a1[j];
        s += __shfl_xor(s, 16);
        s += __shfl_xor(s, 32);
        acc[j] = s;
    }

    if (lane < 16) {
        const int ch = lane * 8;
        float4 b0 = *(const float4*)(bias + ch);
        float4 b1 = *(const float4*)(bias + ch + 4);
        float4 o0, o1;
        o0.x = fmaxf(acc[0] + b0.x, 0.f);
        o0.y = fmaxf(acc[1] + b0.y, 0.f);
        o0.z = fmaxf(acc[2] + b0.z, 0.f);
        o0.w = fmaxf(acc[3] + b0.w, 0.f);
        o1.x = fmaxf(acc[4] + b1.x, 0.f);
        o1.y = fmaxf(acc[5] + b1.y, 0.f);
        o1.z = fmaxf(acc[6] + b1.z, 0.f);
        o1.w = fmaxf(acc[7] + b1.w, 0.f);
        *(float4*)(out + (size_t)r * D + ch) = o0;
        *(float4*)(out + (size_t)r * D + ch + 4) = o1;
    }
}

// ---------------------------------------------------------------------------
extern "C" void kernel_launch(void* const* d_in, const int* in_sizes, int n_in,
                              void* d_out, int out_size, void* d_ws, size_t ws_size,
                              hipStream_t stream) {
    const float* x        = (const float*)d_in[0];
    const int*   adj_rows = (const int*)d_in[1];
    const int*   adj_cols = (const int*)d_in[2];
    const float* adj_vals = (const float*)d_in[3];
    const float* weight   = (const float*)d_in[4];
    const float* bias     = (const float*)d_in[5];
    float*       out      = (float*)d_out;

    const int n = in_sizes[0] / D;   // 100000
    const int e = in_sizes[1];       // 1600000

    // workspace layout
    unsigned short* wi = (unsigned short*)d_ws;                 // n*128 bf16 = 25.6 MB
    size_t off = ((size_t)n * D * sizeof(unsigned short) + 255) & ~(size_t)255;
    int* row_start = (int*)((char*)d_ws + off);
    int* row_end   = row_start + n;
    unsigned short* wbf = (unsigned short*)(row_end + n);       // 32 KB bf16 W

    hipMemsetAsync(row_start, 0xFF, (size_t)n * sizeof(int), stream);
    build_rowptr<<<(e + 255) / 256, 256, 0, stream>>>(adj_rows, weight, wbf,
                                                      row_start, row_end, e);

    gemm_mfma<<<(n + 127) / 128, 256, 0, stream>>>(x, wbf, wi, n);

    spmm_relu<<<(n + 3) / 4, 256, 0, stream>>>(wi, row_start, row_end,
                                               adj_cols, adj_vals, bias, out, n);
}

// Round 4
// 100.922 us; speedup vs baseline: 3.5930x; 1.0370x over previous
//
#include <hip/hip_runtime.h>
#include <hip/hip_bf16.h>

#define D 128
#define RPW 8   // rows per wave in spmm

typedef __attribute__((ext_vector_type(8))) short bf16x8;
typedef __attribute__((ext_vector_type(4))) float f32x4;

// float -> bf16 bits, round-to-nearest-even
__device__ __forceinline__ unsigned short f2bf(float f) {
    union { float f; unsigned u; } uf{f};
    unsigned r = uf.u + 0x7fffu + ((uf.u >> 16) & 1u);
    return (unsigned short)(r >> 16);
}
__device__ __forceinline__ unsigned pack2(float a, float b) {
    return (unsigned)f2bf(a) | ((unsigned)f2bf(b) << 16);
}
__device__ __forceinline__ float bflo(unsigned u) {
    union { unsigned u; float f; } c{u << 16};
    return c.f;
}
__device__ __forceinline__ float bfhi(unsigned u) {
    union { unsigned u; float f; } c{u & 0xffff0000u};
    return c.f;
}

#define FMA8(A, vv, u) \
    A[0] = fmaf(vv, bflo(u.x), A[0]); A[1] = fmaf(vv, bfhi(u.x), A[1]); \
    A[2] = fmaf(vv, bflo(u.y), A[2]); A[3] = fmaf(vv, bfhi(u.y), A[3]); \
    A[4] = fmaf(vv, bflo(u.z), A[4]); A[5] = fmaf(vv, bfhi(u.z), A[5]); \
    A[6] = fmaf(vv, bflo(u.w), A[6]); A[7] = fmaf(vv, bfhi(u.w), A[7]);

// ---------------------------------------------------------------------------
// Kernel 0: rowptr[r] = (start,end) from sorted adj_rows; empty rows filled
//           from the gaps (no memset needed). Also converts W to bf16.
// ---------------------------------------------------------------------------
__global__ __launch_bounds__(256) void build_rowptr(const int* __restrict__ rows,
                                                    const float* __restrict__ W,
                                                    unsigned short* __restrict__ wbf,
                                                    int2* __restrict__ rowptr,
                                                    int e, int n) {
    int i = blockIdx.x * 256 + threadIdx.x;
    if (i < D * D) wbf[i] = f2bf(W[i]);
    if (i >= e) return;
    int r = rows[i];
    int prev = (i == 0) ? -1 : rows[i - 1];
    int next = (i == e - 1) ? n : rows[i + 1];
    if (prev != r) {
        rowptr[r].x = i;
        for (int q = prev + 1; q < r; ++q) rowptr[q] = make_int2(i, i);   // empty rows
    }
    if (next != r) {
        rowptr[r].y = i + 1;
        if (i == e - 1)
            for (int q = r + 1; q < n; ++q) rowptr[q] = make_int2(e, e); // trailing empties
    }
}

// ---------------------------------------------------------------------------
// Kernel 1: wi = bf16(x @ W^T) via MFMA 16x16x32_bf16. LDS-free:
//   A fragments loaded per-lane directly from fp32 x (32B each) and converted
//   in-reg; B fragments from L1-resident 32KB bf16 W.
// ---------------------------------------------------------------------------
__global__ __launch_bounds__(256) void gemm_mfma(const float* __restrict__ x,
                                                 const unsigned short* __restrict__ wbf,
                                                 unsigned short* __restrict__ wi,
                                                 int nrows) {
    const int lane = threadIdx.x & 63;
    const int row0 = blockIdx.x * 128 + (threadIdx.x >> 6) * 32;
    const int lrow = lane & 15;
    const int lk8 = (lane >> 4) * 8;

    bf16x8 afrag[2][4];
#pragma unroll
    for (int rb = 0; rb < 2; ++rb)
#pragma unroll
        for (int kb = 0; kb < 4; ++kb) {
            int gr = min(row0 + rb * 16 + lrow, nrows - 1);
            const float4* p = (const float4*)(x + (size_t)gr * D + kb * 32 + lk8);
            float4 f0 = p[0], f1 = p[1];
            union { bf16x8 v; unsigned u[4]; } cv;
            cv.u[0] = pack2(f0.x, f0.y);
            cv.u[1] = pack2(f0.z, f0.w);
            cv.u[2] = pack2(f1.x, f1.y);
            cv.u[3] = pack2(f1.z, f1.w);
            afrag[rb][kb] = cv.v;
        }

    f32x4 acc[2][8];
#pragma unroll
    for (int rb = 0; rb < 2; ++rb)
#pragma unroll
        for (int nb = 0; nb < 8; ++nb)
            acc[rb][nb] = (f32x4){0.f, 0.f, 0.f, 0.f};

#pragma unroll
    for (int nb = 0; nb < 8; ++nb) {
#pragma unroll
        for (int kb = 0; kb < 4; ++kb) {
            bf16x8 bfrag = *(const bf16x8*)(wbf + (nb * 16 + lrow) * 128 + kb * 32 + lk8);
            acc[0][nb] = __builtin_amdgcn_mfma_f32_16x16x32_bf16(afrag[0][kb], bfrag, acc[0][nb], 0, 0, 0);
            acc[1][nb] = __builtin_amdgcn_mfma_f32_16x16x32_bf16(afrag[1][kb], bfrag, acc[1][nb], 0, 0, 0);
        }
    }

    // C/D layout: col = lane&15, row = (lane>>4)*4 + j
#pragma unroll
    for (int rb = 0; rb < 2; ++rb)
#pragma unroll
        for (int j = 0; j < 4; ++j) {
            int gr = row0 + rb * 16 + (lane >> 4) * 4 + j;
            if (gr < nrows) {
#pragma unroll
                for (int nb = 0; nb < 8; ++nb)
                    wi[(size_t)gr * D + nb * 16 + lrow] = f2bf(acc[rb][nb][j]);
            }
        }
}

// ---------------------------------------------------------------------------
// Kernel 2: out[r] = relu(bias + sum vals[e]*wi[cols[e]])  (wi is bf16)
//   8 rows per wave, software-pipelined: next row's cols/vals issued before
//   processing current row's gathers. Rowptrs fetched lane-parallel (1 load).
// ---------------------------------------------------------------------------
__global__ __launch_bounds__(256) void spmm_relu(const unsigned short* __restrict__ wi,
                                                 const int2* __restrict__ rowptr,
                                                 const int* __restrict__ cols,
                                                 const float* __restrict__ vals,
                                                 const float* __restrict__ bias,
                                                 float* __restrict__ out,
                                                 int n) {
    const int lane = threadIdx.x & 63;
    const int R0 = (blockIdx.x * 4 + (threadIdx.x >> 6)) * RPW;
    if (R0 >= n) return;
    const int nr = min(RPW, n - R0);

    const int2 rp = rowptr[R0 + min(lane, nr - 1)];
    const int ch = (lane & 15) * 8;   // channel base this lane gathers
    const int sub = lane >> 4;        // which edge of each quad

    // bias for the store lanes
    float4 b0 = *(const float4*)(bias + (lane & 15) * 8);
    float4 b1 = *(const float4*)(bias + (lane & 15) * 8 + 4);

    // prologue: stage row 0's first chunk
    int s = __shfl(rp.x, 0), e = __shfl(rp.y, 0);
    int c = 0; float v = 0.f;
    { int idx = s + lane; if (idx < e) { c = cols[idx]; v = vals[idx]; } }

    for (int j = 0; j < nr; ++j) {
        // issue next row's metadata loads early (hide latency under this row)
        int s_n = 0, e_n = 0, c_n = 0; float v_n = 0.f;
        if (j + 1 < nr) {
            s_n = __shfl(rp.x, j + 1); e_n = __shfl(rp.y, j + 1);
            int idx = s_n + lane; if (idx < e_n) { c_n = cols[idx]; v_n = vals[idx]; }
        }

        float a0[8] = {0.f, 0.f, 0.f, 0.f, 0.f, 0.f, 0.f, 0.f};
        float a1[8] = {0.f, 0.f, 0.f, 0.f, 0.f, 0.f, 0.f, 0.f};

        const int cnt = min(e - s, 64);
        for (int q = 0; q * 4 < cnt; q += 4) {
            const int i0 = q * 4 + sub;
            int   c0 = __shfl(c, i0),     c1 = __shfl(c, i0 + 4);
            int   c2 = __shfl(c, i0 + 8), c3 = __shfl(c, i0 + 12);
            float v0 = __shfl(v, i0),     v1 = __shfl(v, i0 + 4);
            float v2 = __shfl(v, i0 + 8), v3 = __shfl(v, i0 + 12);
            uint4 u0 = *(const uint4*)(wi + (size_t)c0 * D + ch);
            uint4 u1 = *(const uint4*)(wi + (size_t)c1 * D + ch);
            uint4 u2 = *(const uint4*)(wi + (size_t)c2 * D + ch);
            uint4 u3 = *(const uint4*)(wi + (size_t)c3 * D + ch);
            FMA8(a0, v0, u0); FMA8(a1, v1, u1);
            FMA8(a0, v2, u2); FMA8(a1, v3, u3);
        }
        // rare rows with >64 edges
        for (int base = s + 64; base < e; base += 64) {
            int cc = 0; float vv = 0.f;
            { int idx = base + lane; if (idx < e) { cc = cols[idx]; vv = vals[idx]; } }
            const int cnt2 = min(e - base, 64);
            for (int q = 0; q * 4 < cnt2; q += 4) {
                const int i0 = q * 4 + sub;
                int   c0 = __shfl(cc, i0),     c1 = __shfl(cc, i0 + 4);
                int   c2 = __shfl(cc, i0 + 8), c3 = __shfl(cc, i0 + 12);
                float v0 = __shfl(vv, i0),     v1 = __shfl(vv, i0 + 4);
                float v2 = __shfl(vv, i0 + 8), v3 = __shfl(vv, i0 + 12);
                uint4 u0 = *(const uint4*)(wi + (size_t)c0 * D + ch);
                uint4 u1 = *(const uint4*)(wi + (size_t)c1 * D + ch);
                uint4 u2 = *(const uint4*)(wi + (size_t)c2 * D + ch);
                uint4 u3 = *(const uint4*)(wi + (size_t)c3 * D + ch);
                FMA8(a0, v0, u0); FMA8(a1, v1, u1);
                FMA8(a0, v2, u2); FMA8(a1, v3, u3);
            }
        }

        // cross-subgroup reduce + store this row
        float r8[8];
#pragma unroll
        for (int t = 0; t < 8; ++t) {
            float sjj = a0[t] + a1[t];
            sjj += __shfl_xor(sjj, 16);
            sjj += __shfl_xor(sjj, 32);
            r8[t] = sjj;
        }
        if (lane < 16) {
            float4 o0, o1;
            o0.x = fmaxf(r8[0] + b0.x, 0.f);
            o0.y = fmaxf(r8[1] + b0.y, 0.f);
            o0.z = fmaxf(r8[2] + b0.z, 0.f);
            o0.w = fmaxf(r8[3] + b0.w, 0.f);
            o1.x = fmaxf(r8[4] + b1.x, 0.f);
            o1.y = fmaxf(r8[5] + b1.y, 0.f);
            o1.z = fmaxf(r8[6] + b1.z, 0.f);
            o1.w = fmaxf(r8[7] + b1.w, 0.f);
            *(float4*)(out + (size_t)(R0 + j) * D + lane * 8) = o0;
            *(float4*)(out + (size_t)(R0 + j) * D + lane * 8 + 4) = o1;
        }

        s = s_n; e = e_n; c = c_n; v = v_n;
    }
}

// ---------------------------------------------------------------------------
extern "C" void kernel_launch(void* const* d_in, const int* in_sizes, int n_in,
                              void* d_out, int out_size, void* d_ws, size_t ws_size,
                              hipStream_t stream) {
    const float* x        = (const float*)d_in[0];
    const int*   adj_rows = (const int*)d_in[1];
    const int*   adj_cols = (const int*)d_in[2];
    const float* adj_vals = (const float*)d_in[3];
    const float* weight   = (const float*)d_in[4];
    const float* bias     = (const float*)d_in[5];
    float*       out      = (float*)d_out;

    const int n = in_sizes[0] / D;   // 100000
    const int e = in_sizes[1];       // 1600000

    // workspace layout
    unsigned short* wi = (unsigned short*)d_ws;                 // n*128 bf16 = 25.6 MB
    size_t off = ((size_t)n * D * sizeof(unsigned short) + 255) & ~(size_t)255;
    int2* rowptr = (int2*)((char*)d_ws + off);                  // n int2 = 0.8 MB
    unsigned short* wbf = (unsigned short*)(rowptr + n);        // 32 KB bf16 W

    build_rowptr<<<(e + 255) / 256, 256, 0, stream>>>(adj_rows, weight, wbf,
                                                      rowptr, e, n);

    gemm_mfma<<<(n + 127) / 128, 256, 0, stream>>>(x, wbf, wi, n);

    const int rows_per_block = 4 * RPW;
    spmm_relu<<<(n + rows_per_block - 1) / rows_per_block, 256, 0, stream>>>(
        wi, rowptr, adj_cols, adj_vals, bias, out, n);
}